// Round 1
// 487.705 us; speedup vs baseline: 1.3664x; 1.3664x over previous
//
#include <hip/hip_runtime.h>
#include <hip/hip_bf16.h>

#define B_  2
#define T_  2048
#define H_  2048
#define NH_ 16
#define HD_ 128

typedef __attribute__((ext_vector_type(8))) short  short8;   // 8 bf16 in 4 VGPRs
typedef __attribute__((ext_vector_type(4))) float  floatx4;  // MFMA C/D

__device__ __forceinline__ unsigned short f2bf(float x) {
    union { float f; unsigned int u; } c; c.f = x;
    unsigned int r = c.u + 0x7FFF + ((c.u >> 16) & 1);   // RNE
    return (unsigned short)(r >> 16);
}
__device__ __forceinline__ float bf2f(unsigned short u) {
    union { float f; unsigned int i; } c;
    c.i = ((unsigned int)u) << 16;
    return c.f;
}

// async global->LDS, 16B per lane; LDS dest is wave-uniform base + lane*16
__device__ __forceinline__ void gload_lds16(const void* g, void* l) {
    __builtin_amdgcn_global_load_lds(
        (__attribute__((address_space(1))) void*)g,
        (__attribute__((address_space(3))) void*)l, 16, 0, 0);
}

// ---------------- fp32 -> bf16 convert (vector4) ---------------------------------
__global__ __launch_bounds__(256) void f32_to_bf16(
    const float* __restrict__ src, unsigned short* __restrict__ dst, int n)
{
    const int i = (blockIdx.x * 256 + threadIdx.x) * 4;
    if (i < n) {
        float4 v = *(const float4*)(src + i);
        ushort4 o;
        o.x = f2bf(v.x); o.y = f2bf(v.y); o.z = f2bf(v.z); o.w = f2bf(v.w);
        *(ushort4*)(dst + i) = o;
    }
}

// ---------------- bf16 MFMA GEMM: Y[M,N] = A[M,K] @ W[N,K]^T ---------------------
// m97 structure: 128x128 tile, BK=32, global_load_lds(16B), 4 waves x 4x4 MFMA tiles.
template<bool BF16_OUT>
__global__ __launch_bounds__(256) void gemm_mfma(
    const unsigned short* __restrict__ A,   // [M,K] bf16
    const unsigned short* __restrict__ W,   // [N,K] bf16
    float* __restrict__ Yf, unsigned short* __restrict__ Yb,
    int M, int N, int K)
{
    __shared__ __attribute__((aligned(16))) unsigned short Ah[128 * 32];
    __shared__ __attribute__((aligned(16))) unsigned short Bh[128 * 32];

    const int tid  = threadIdx.x;
    const int lane = tid & 63;
    const int n16  = lane & 15;
    const int quad = lane >> 4;
    const int w    = tid >> 6;
    const int wm   = w & 1, wn = w >> 1;

    const int m0 = blockIdx.y * 128;
    const int n0 = blockIdx.x * 128;

    const int srow = tid >> 2;          // staging row 0..63
    const int scol = (tid & 3) * 8;     // staging k-offset (bf16 units)

    floatx4 acc[4][4];
    #pragma unroll
    for (int i = 0; i < 4; i++)
        #pragma unroll
        for (int j = 0; j < 4; j++) acc[i][j] = (floatx4){0.f, 0.f, 0.f, 0.f};

    for (int k0 = 0; k0 < K; k0 += 32) {
        __syncthreads();
        gload_lds16(A + (size_t)(m0 +      srow) * K + k0 + scol, Ah + (size_t)tid * 8);
        gload_lds16(A + (size_t)(m0 + 64 + srow) * K + k0 + scol, Ah + (size_t)(tid + 256) * 8);
        gload_lds16(W + (size_t)(n0 +      srow) * K + k0 + scol, Bh + (size_t)tid * 8);
        gload_lds16(W + (size_t)(n0 + 64 + srow) * K + k0 + scol, Bh + (size_t)(tid + 256) * 8);
        __syncthreads();   // compiler drains vmcnt before s_barrier

        short8 af[4], bfr[4];
        #pragma unroll
        for (int i = 0; i < 4; i++) {
            af[i]  = *(const short8*)(Ah + (wm * 64 + i * 16 + n16) * 32 + quad * 8);
            bfr[i] = *(const short8*)(Bh + (wn * 64 + i * 16 + n16) * 32 + quad * 8);
        }
        #pragma unroll
        for (int i = 0; i < 4; i++)
            #pragma unroll
            for (int j = 0; j < 4; j++)
                acc[i][j] = __builtin_amdgcn_mfma_f32_16x16x32_bf16(af[i], bfr[j], acc[i][j], 0, 0, 0);
    }

    // C/D: col = lane&15, row = quad*4 + reg  (verified m89/m91)
    #pragma unroll
    for (int i = 0; i < 4; i++) {
        const int rbase = m0 + wm * 64 + i * 16 + quad * 4;
        #pragma unroll
        for (int r = 0; r < 4; r++) {
            const size_t row = rbase + r;
            #pragma unroll
            for (int j = 0; j < 4; j++) {
                const size_t col = n0 + wn * 64 + j * 16 + n16;
                if (BF16_OUT) Yb[row * N + col] = f2bf(acc[i][j][r]);
                else          Yf[row * N + col] = acc[i][j][r];
            }
        }
    }
}

// ---------------- RoPE: bf16 [B,T,H] -> bf16 [BH][T][HD] (q scaled) --------------
__global__ __launch_bounds__(256) void rope_convert_qk(
    const unsigned short* __restrict__ qp, const unsigned short* __restrict__ kp,
    const float* __restrict__ cosp, const float* __restrict__ sinp,
    unsigned short* __restrict__ qh, unsigned short* __restrict__ kh)
{
    const int idx  = blockIdx.x * 256 + threadIdx.x;
    const int d    = idx & 63;
    const int rest = idx >> 6;
    const int h    = rest & 15;
    const int bt   = rest >> 4;
    const int t    = bt & (T_ - 1);
    const int b    = bt >> 11;                       // T_ = 2048
    const size_t ibase = (size_t)bt * H_ + h * HD_;
    const size_t obase = (((size_t)b * NH_ + h) * T_ + t) * HD_;

    const float c0 = cosp[t*HD_ + d],      s0 = sinp[t*HD_ + d];
    const float c1 = cosp[t*HD_ + d + 64], s1 = sinp[t*HD_ + d + 64];
    const float sc = 0.08838834764831845f;           // 1/sqrt(128)

    float q0 = bf2f(qp[ibase + d]), q1 = bf2f(qp[ibase + d + 64]);
    qh[obase + d]      = f2bf((q0*c0 - q1*s0) * sc);
    qh[obase + d + 64] = f2bf((q1*c1 + q0*s1) * sc);

    float k0 = bf2f(kp[ibase + d]), k1 = bf2f(kp[ibase + d + 64]);
    kh[obase + d]      = f2bf(k0*c0 - k1*s0);
    kh[obase + d + 64] = f2bf(k1*c1 + k0*s1);
}

// ---------------- V transpose: bf16 [B,T,H] -> bf16 [BH][HD][T] ------------------
__global__ __launch_bounds__(256) void transpose_v(
    const unsigned short* __restrict__ vb, unsigned short* __restrict__ vh)
{
    __shared__ float tile[64][65];
    const int t0 = blockIdx.x * 64;
    const int d0 = blockIdx.y * 64;
    const int bh = blockIdx.z;
    const int b  = bh >> 4, h = bh & 15;

    for (int i = threadIdx.x; i < 4096; i += 256) {
        int r = i >> 6, c = i & 63;
        tile[r][c] = bf2f(vb[((size_t)b*T_ + t0 + r) * H_ + h*HD_ + d0 + c]);
    }
    __syncthreads();
    for (int i = threadIdx.x; i < 4096; i += 256) {
        int dr = i >> 6, tc = i & 63;
        vh[((size_t)bh * HD_ + d0 + dr) * T_ + t0 + tc] = f2bf(tile[tc][dr]);  // exact round-trip
    }
}

// ---------------- MFMA flash attention ------------------------------------------
// Round-6: linear swizzled LDS (granule^=row&7, both-sides with pre-swizzled
// global_load_lds source), 40KB LDS -> 4 blocks/CU, work-balanced qblk remap
// (per-CU {a,a+8,23-a,31-a}: exactly 66 tile-units/CU, shared bh per CU),
// diagonal-only masking.
__global__ __launch_bounds__(256, 4) void attn_mfma(
    const unsigned short* __restrict__ qh,   // [BH][T][HD] (pre-scaled)
    const unsigned short* __restrict__ kh,   // [BH][T][HD]
    const unsigned short* __restrict__ vh,   // [BH][HD][T]
    unsigned short* __restrict__ o)          // [B][T][H] bf16
{
    __shared__ __attribute__((aligned(16))) unsigned short Ks[64 * 128];   // 16 KB
    __shared__ __attribute__((aligned(16))) unsigned short Vs[128 * 64];   // 16 KB
    __shared__ __attribute__((aligned(16))) unsigned short Ps[4][16 * 64]; //  8 KB

    const int tid  = threadIdx.x;
    const int lane = tid & 63;
    const int w    = tid >> 6;
    const int n16  = lane & 15;
    const int quad = lane >> 4;

    // work-balanced bijective remap: id -> (qblk, bh).
    // ids {c, c+256, c+512, c+768} (one CU under linear round-robin) get
    // qblk {a, a+8, 23-a, 31-a} -> (sum+4) = 66 tiles on every CU; bh = id&31
    // is identical for all 4 -> they share K/V streams in L2.
    const int id   = blockIdx.y * gridDim.x + blockIdx.x;
    const int bh   = id & 31;
    const int a    = (id >> 5) & 7;
    const int u    = id >> 8;
    const int qblk = (u < 2) ? (a + (u << 3)) : ((23 + ((u & 1) << 3)) - a);

    const int q0w  = qblk * 64 + w * 16;

    short8 qf[4];
    {
        const size_t qbase = ((size_t)bh * T_ + q0w + n16) * HD_ + quad * 8;
        #pragma unroll
        for (int c = 0; c < 4; c++)
            qf[c] = *(const short8*)(qh + qbase + c * 32);
    }

    // pre-swizzled per-lane global sources for global_load_lds staging.
    // K slot s = it*256+tid: row = it*16 + (tid>>4), granule = tid&15;
    //   source granule = (tid&15) ^ (row&7); (it*16 % 8 == 0 -> it-independent)
    const int rk   = tid >> 4;
    const int gk16 = ((tid & 15) ^ (rk & 7)) * 8;
    const unsigned short* ksrc = kh + (size_t)bh * T_ * HD_ + (size_t)rk * HD_ + gk16;
    // V slot s: d = it*32 + (tid>>3), granule = tid&7; source granule = g ^ (d&7)
    const int dv   = tid >> 3;
    const int gv16 = ((tid & 7) ^ (dv & 7)) * 8;
    const unsigned short* vsrc = vh + (size_t)bh * HD_ * T_ + (size_t)dv * T_ + gv16;

    floatx4 of[8];
    #pragma unroll
    for (int i = 0; i < 8; i++) of[i] = (floatx4){0.f, 0.f, 0.f, 0.f};
    float mrow[4], lrow[4];
    #pragma unroll
    for (int r = 0; r < 4; r++) { mrow[r] = -INFINITY; lrow[r] = 0.f; }

    const int nkv = qblk + 1;
    for (int kv = 0; kv < nkv; kv++) {
        const int kv0 = kv * 64;
        __syncthreads();
        #pragma unroll
        for (int it = 0; it < 4; it++)
            gload_lds16(ksrc + (size_t)(kv0 + it * 16) * HD_,
                        Ks + (size_t)(it * 256 + tid) * 8);
        #pragma unroll
        for (int it = 0; it < 4; it++)
            gload_lds16(vsrc + kv0 + (size_t)(it * 32) * T_,
                        Vs + (size_t)(it * 256 + tid) * 8);
        __syncthreads();   // compiler drains vmcnt(0) before s_barrier

        floatx4 s[4];
        #pragma unroll
        for (int kg = 0; kg < 4; kg++) {
            floatx4 acc = {0.f, 0.f, 0.f, 0.f};
            #pragma unroll
            for (int c = 0; c < 4; c++) {
                short8 kf = *(const short8*)(Ks + (kg*16 + n16) * 128
                                                + (((c*4 + quad) ^ (n16 & 7)) * 8));
                acc = __builtin_amdgcn_mfma_f32_16x16x32_bf16(qf[c], kf, acc, 0, 0, 0);
            }
            s[kg] = acc;
        }

        // only the diagonal tile needs causal masking (wave-uniform branch)
        const bool needmask = (kv0 + 63 > q0w);

        float alpha[4];
        #pragma unroll
        for (int r = 0; r < 4; r++) {
            const int qrow = q0w + quad * 4 + r;
            float v0 = s[0][r], v1 = s[1][r], v2 = s[2][r], v3 = s[3][r];
            if (needmask) {
                if (kv0 +  0 + n16 > qrow) v0 = -INFINITY;
                if (kv0 + 16 + n16 > qrow) v1 = -INFINITY;
                if (kv0 + 32 + n16 > qrow) v2 = -INFINITY;
                if (kv0 + 48 + n16 > qrow) v3 = -INFINITY;
            }

            float tm = fmaxf(fmaxf(v0, v1), fmaxf(v2, v3));
            tm = fmaxf(tm, __shfl_xor(tm, 1));
            tm = fmaxf(tm, __shfl_xor(tm, 2));
            tm = fmaxf(tm, __shfl_xor(tm, 4));
            tm = fmaxf(tm, __shfl_xor(tm, 8));

            const float mnew = fmaxf(mrow[r], tm);
            const float aa   = __expf(mrow[r] - mnew);
            const float p0 = __expf(v0 - mnew), p1 = __expf(v1 - mnew);
            const float p2 = __expf(v2 - mnew), p3 = __expf(v3 - mnew);

            float ts = p0 + p1 + p2 + p3;
            ts += __shfl_xor(ts, 1);
            ts += __shfl_xor(ts, 2);
            ts += __shfl_xor(ts, 4);
            ts += __shfl_xor(ts, 8);

            lrow[r] = lrow[r] * aa + ts;
            mrow[r] = mnew;
            alpha[r] = aa;

            // Ps row pr, col c stored at granule (c>>3)^(pr&7), byte (c&7)
            const int pr = quad * 4 + r;
            const int sx = pr & 7;
            unsigned short* pp = &Ps[w][pr * 64];
            const int g0 = n16 >> 3, e = n16 & 7;
            pp[((g0    ) ^ sx) * 8 + e] = f2bf(p0);
            pp[((g0 + 2) ^ sx) * 8 + e] = f2bf(p1);
            pp[((g0 + 4) ^ sx) * 8 + e] = f2bf(p2);
            pp[((g0 + 6) ^ sx) * 8 + e] = f2bf(p3);
        }
        #pragma unroll
        for (int nt = 0; nt < 8; nt++)
            #pragma unroll
            for (int r = 0; r < 4; r++) of[nt][r] *= alpha[r];

        short8 pf0 = *(const short8*)(&Ps[w][n16 * 64 + ((quad       ^ (n16 & 7)) * 8)]);
        short8 pf1 = *(const short8*)(&Ps[w][n16 * 64 + (((quad + 4) ^ (n16 & 7)) * 8)]);
        #pragma unroll
        for (int nt = 0; nt < 8; nt++) {
            const int vr = (nt * 16 + n16) * 64;
            short8 vf0 = *(const short8*)(Vs + vr + ((quad       ^ (n16 & 7)) * 8));
            short8 vf1 = *(const short8*)(Vs + vr + (((quad + 4) ^ (n16 & 7)) * 8));
            of[nt] = __builtin_amdgcn_mfma_f32_16x16x32_bf16(pf0, vf0, of[nt], 0, 0, 0);
            of[nt] = __builtin_amdgcn_mfma_f32_16x16x32_bf16(pf1, vf1, of[nt], 0, 0, 0);
        }
    }

    const int b = bh >> 4, h = bh & 15;
    #pragma unroll
    for (int r = 0; r < 4; r++) {
        const float inv = 1.f / lrow[r];
        const size_t orow = ((size_t)b * T_ + q0w + quad*4 + r) * H_ + h * HD_;
        #pragma unroll
        for (int nt = 0; nt < 8; nt++)
            o[orow + nt*16 + n16] = f2bf(of[nt][r] * inv);
    }
}

extern "C" void kernel_launch(void* const* d_in, const int* in_sizes, int n_in,
                              void* d_out, int out_size, void* d_ws, size_t ws_size,
                              hipStream_t stream)
{
    const float* x    = (const float*)d_in[0];
    const float* cosp = (const float*)d_in[1];
    const float* sinp = (const float*)d_in[2];
    const float* Wq   = (const float*)d_in[3];
    const float* Wk   = (const float*)d_in[4];
    const float* Wv   = (const float*)d_in[5];
    const float* Wo   = (const float*)d_in[6];

    const size_t NEL  = (size_t)B_ * T_ * H_;   // 8388608
    const size_t NB   = NEL * 4;                // 33.5 MB
    const int    XN   = (int)NEL;               // x elements
    const int    WN   = H_ * H_;                // 4194304 per weight
    char* ws = (char*)d_ws;

    // overlay plan (total 4*NB = 134 MB, proven footprint):
    unsigned short* xh   = (unsigned short*)(ws);                 // [0, NB/2)
    unsigned short* Woh  = (unsigned short*)(ws + NB/2);          // NB/4
    unsigned short* Wqh  = (unsigned short*)(ws + 3*NB/4);        // NB/4
    unsigned short* Wkh  = (unsigned short*)(ws + NB);            // NB/4
    unsigned short* Wvh  = (unsigned short*)(ws + 5*NB/4);        // NB/4
    unsigned short* qpre = (unsigned short*)(ws + 3*NB/2);        // NB/2
    unsigned short* kpre = (unsigned short*)(ws + 2*NB);          // NB/2
    unsigned short* vpre = (unsigned short*)(ws + 5*NB/2);        // NB/2
    unsigned short* qh   = (unsigned short*)(ws + 3*NB);          // NB/2
    unsigned short* kh   = (unsigned short*)(ws + 7*NB/2);        // NB/2
    unsigned short* vh   = (unsigned short*)(ws);                 // overlays dead xh
    unsigned short* abh  = (unsigned short*)(ws + 3*NB/2);        // overlays dead qpre

    f32_to_bf16<<<XN/1024, 256, 0, stream>>>(x,  xh,  XN);
    f32_to_bf16<<<WN/1024, 256, 0, stream>>>(Wq, Wqh, WN);
    f32_to_bf16<<<WN/1024, 256, 0, stream>>>(Wk, Wkh, WN);
    f32_to_bf16<<<WN/1024, 256, 0, stream>>>(Wv, Wvh, WN);
    f32_to_bf16<<<WN/1024, 256, 0, stream>>>(Wo, Woh, WN);

    const int M = B_ * T_, N = H_, K = H_;
    dim3 gg(N / 128, M / 128);

    gemm_mfma<true><<<gg, 256, 0, stream>>>(xh, Wqh, nullptr, qpre, M, N, K);
    gemm_mfma<true><<<gg, 256, 0, stream>>>(xh, Wkh, nullptr, kpre, M, N, K);
    gemm_mfma<true><<<gg, 256, 0, stream>>>(xh, Wvh, nullptr, vpre, M, N, K);

    rope_convert_qk<<<(B_*T_*NH_*64)/256, 256, 0, stream>>>(qpre, kpre, cosp, sinp, qh, kh);
    transpose_v<<<dim3(T_/64, HD_/64, B_*NH_), 256, 0, stream>>>(vpre, vh);

    attn_mfma<<<dim3(T_/64, B_*NH_), 256, 0, stream>>>(qh, kh, vh, abh);

    gemm_mfma<false><<<gg, 256, 0, stream>>>(abh, Woh, (float*)d_out, nullptr, M, N, K);
}